// Round 4
// baseline (532.559 us; speedup 1.0000x reference)
//
#include <hip/hip_runtime.h>

#define N_SUP 4096
#define N_QRY 8192
#define IN_DIM 784
#define EMB 512
#define NCLS 64
#define M_TOT (N_SUP + N_QRY)
#define NCHUNK 25   // ceil(784/32)
#define XCH 13      // ceil(784/64)

typedef _Float16 f16;
typedef _Float16 f16x8 __attribute__((ext_vector_type(8)));
typedef float f32x4 __attribute__((ext_vector_type(4)));

// async global->LDS, 16B per lane. LDS dest is wave-uniform base + lane*16.
#define GLDS16(gp, lp)                                                        \
    __builtin_amdgcn_global_load_lds(                                         \
        (const __attribute__((address_space(1))) void*)(gp),                  \
        (__attribute__((address_space(3))) void*)(lp), 16, 0, 0)

// load 8 consecutive fp32 and convert to f16x8
static __device__ __forceinline__ f16x8 cvt8(const float* p) {
    float4 a = *(const float4*)p;
    float4 b = *(const float4*)(p + 4);
    f16x8 v;
    v[0] = (f16)a.x; v[1] = (f16)a.y; v[2] = (f16)a.z; v[3] = (f16)a.w;
    v[4] = (f16)b.x; v[5] = (f16)b.y; v[6] = (f16)b.z; v[7] = (f16)b.w;
    return v;
}

// ---- fused prep: blocks [0,200) = Wb repack, [200,1224) = label argmax ----
__global__ __launch_bounds__(256) void pre_enc(const float* __restrict__ W,
                                               const float* __restrict__ lab,
                                               f16* __restrict__ Wb,
                                               int* __restrict__ lbl) {
    if (blockIdx.x < 200) {
        int g = blockIdx.x * 256 + threadIdx.x;      // 51200 frag-lanes
        if (g >= NCHUNK * 32 * 64) return;
        int chunk = g >> 11;
        int rem = g & 2047;
        int nbg = rem >> 6, lane = rem & 63;
        int n = nbg * 16 + (lane & 15);
        int kbase = chunk * 32 + (lane >> 4) * 8;
        f16x8 v;
#pragma unroll
        for (int j = 0; j < 8; ++j) {
            int k = kbase + j;
            v[j] = (k < IN_DIM) ? (f16)W[(size_t)k * EMB + n] : (f16)0.f;
        }
        *(f16x8*)(Wb + (size_t)g * 8) = v;
    } else {
        const int w = threadIdx.x >> 6, lane = threadIdx.x & 63;
        const int s = (blockIdx.x - 200) * 4 + w;
        float v = lab[(size_t)s * NCLS + lane];
        int c = lane;
#pragma unroll
        for (int off = 1; off < 64; off <<= 1) {
            float v2 = __shfl_xor(v, off);
            int c2 = __shfl_xor(c, off);
            if (v2 > v || (v2 == v && c2 < c)) { v = v2; c = c2; }
        }
        if (lane == 0) lbl[s] = c;
    }
}

// ---- encode: 32 rows x 256 cols per block, grid 768 (3 blocks/CU). ----
__global__ __launch_bounds__(256) void encode(
    const float* __restrict__ sup, const float* __restrict__ qry,
    const f16* __restrict__ Wb, const float* __restrict__ bias,
    f16* __restrict__ E, float* __restrict__ norms)
{
    __shared__ __align__(16) f16 Xs[32][72];
    const int tid = threadIdx.x;
    const int w = tid >> 6, lane = tid & 63;
    const int q = lane >> 4, c16 = lane & 15;
    const int mb = blockIdx.x >> 1;
    const int ch = blockIdx.x & 1;
    const int m0 = mb * 32;
    const int rbase = (w & 1) * 16;
    const int nbg0 = ch * 16 + (w >> 1) * 8;
    const int cbase = nbg0 * 16;

    f32x4 acc[8];
#pragma unroll
    for (int nb = 0; nb < 8; ++nb) acc[nb] = (f32x4){0.f, 0.f, 0.f, 0.f};

    const int sr = tid >> 3;
    const int sq = tid & 7;
    const float* xrow;
    {
        int gr = m0 + sr;
        xrow = (gr < N_SUP) ? sup + (size_t)gr * IN_DIM
                            : qry + (size_t)(gr - N_SUP) * IN_DIM;
    }

    f16x8 xg = cvt8(xrow + sq * 8);

    for (int c = 0; c < XCH; ++c) {
        __syncthreads();
        *(f16x8*)&Xs[sr][sq * 8] = xg;
        __syncthreads();
        if (c + 1 < XCH) {
            int k = (c + 1) * 64 + sq * 8;
            xg = (k + 8 <= IN_DIM) ? cvt8(xrow + k) : (f16x8){0,0,0,0,0,0,0,0};
        }
#pragma unroll
        for (int kc = 0; kc < 2; ++kc) {
            int c32 = c * 2 + kc;
            if (c32 >= NCHUNK) break;
            f16x8 a = *(const f16x8*)&Xs[rbase + c16][kc * 32 + q * 8];
            const f16* wb = Wb + ((size_t)(c32 * 32 + nbg0) * 64 + lane) * 8;
#pragma unroll
            for (int nb = 0; nb < 8; ++nb) {
                f16x8 b = *(const f16x8*)(wb + (size_t)nb * 512);
                acc[nb] = __builtin_amdgcn_mfma_f32_16x16x32_f16(a, b, acc[nb], 0, 0, 0);
            }
        }
    }

    float nrm[4] = {0.f, 0.f, 0.f, 0.f};
#pragma unroll
    for (int nb = 0; nb < 8; ++nb) {
        int col = cbase + nb * 16 + c16;
        float bv = bias[col];
#pragma unroll
        for (int r = 0; r < 4; ++r) {
            int row = m0 + rbase + q * 4 + r;
            float v = acc[nb][r] + bv;
            E[(size_t)row * EMB + col] = (f16)v;
            nrm[r] += v * v;
        }
    }
#pragma unroll
    for (int r = 0; r < 4; ++r) {
        float v = nrm[r];
        v += __shfl_xor(v, 1); v += __shfl_xor(v, 2);
        v += __shfl_xor(v, 4); v += __shfl_xor(v, 8);
        if (c16 == 0) atomicAdd(&norms[m0 + rbase + q * 4 + r], v);
    }
}

// ---- fused post-encode: [0,1024) Sb swizzle, [1024,3072) anchor,
//      [3072,4096) Lcs one-hot transpose ----
__global__ __launch_bounds__(256) void post_enc(
    const f16* __restrict__ E, const float* __restrict__ norms,
    const int* __restrict__ lbl, f16* __restrict__ Sb,
    f16* __restrict__ Lcs, float* __restrict__ manc)
{
    const int b = blockIdx.x;
    if (b < 1024) {
        int g = b * 256 + threadIdx.x;   // 262144 groups of 8 f16
        int s = g >> 6, lg = g & 63;
        f16x8 v = *(const f16x8*)(E + (size_t)s * EMB + lg * 8);
        *(f16x8*)(Sb + (size_t)s * EMB + ((lg ^ (s & 15)) * 8)) = v;
    } else if (b < 3072) {
        const int w = threadIdx.x >> 6, lane = threadIdx.x & 63;
        const int qrow = (b - 1024) * 4 + w;
        f16x8 qv = *(const f16x8*)(E + (size_t)(N_SUP + qrow) * EMB + lane * 8);
        f16x8 sv = *(const f16x8*)(E + lane * 8);
        float dot = 0.f;
#pragma unroll
        for (int j = 0; j < 8; ++j) dot += (float)qv[j] * (float)sv[j];
        dot += __shfl_xor(dot, 1);  dot += __shfl_xor(dot, 2);
        dot += __shfl_xor(dot, 4);  dot += __shfl_xor(dot, 8);
        dot += __shfl_xor(dot, 16); dot += __shfl_xor(dot, 32);
        if (lane == 0) {
            float d2 = fmaxf(norms[N_SUP + qrow] + norms[0] - 2.f * dot, 0.f);
            manc[qrow] = sqrtf(d2);
        }
    } else {
        int idx = (b - 3072) * 256 + threadIdx.x;
        int c = idx >> 12, s = idx & (N_SUP - 1);
        Lcs[idx] = (lbl[s] == c) ? (f16)1.f : (f16)0.f;
    }
}

// QK over K=512 for one 16-support tile from base pointer `bsrc` (LDS copy or
// the identical linear Sb tile in global). Dual accumulator chains halve the
// dependent-MFMA latency (two independent 8-chains).
#define QK_BODY(bsrc, a0, a1)                                                 \
    _Pragma("unroll")                                                         \
    for (int kc = 0; kc < 4; ++kc) {                                          \
        _Pragma("unroll")                                                     \
        for (int ksl = 0; ksl < 4; ++ksl) {                                   \
            const int lg = kc * 16 + ksl * 4 + q;                             \
            f16x8 bfr = *(const f16x8*)&(bsrc)[c16 * EMB + ((lg ^ c16) * 8)]; \
            if (ksl & 1)                                                      \
                a1 = __builtin_amdgcn_mfma_f32_16x16x32_f16(                  \
                    qf[kc * 4 + ksl], bfr, a1, 0, 0, 0);                      \
            else                                                              \
                a0 = __builtin_amdgcn_mfma_f32_16x16x32_f16(                  \
                    qf[kc * 4 + ksl], bfr, a0, 0, 0, 0);                      \
        }                                                                     \
    }

// ---- attn v5: v3 structure (best: 86.4us) + split-source broadcast +
// dual-chain QK + setprio. Counters said LDS-read is the tallest pole
// (16 waves x 16 ds_read_b128/tile = 47% pipe busy; 4x intra-block
// broadcast of each S-tile). Wave 3 reads its B-frags straight from
// L2-hot Sb (identical linear layout + baked-in XOR swizzle), cutting
// LDS demand 25% and moving it to the ~23%-busy L2 pipe.
__global__ __launch_bounds__(256, 3) void attn(
    const f16* __restrict__ E, const float* __restrict__ norms,
    const float* __restrict__ manc, const f16* __restrict__ Lcs,
    const f16* __restrict__ Sb, float* __restrict__ Num)
{
    __shared__ __align__(16) f16 Ss[2][16 * EMB];   // 2 x 16KB
    __shared__ __align__(16) f16 Pt[4][16][40];     // per-wave P transpose, 5KB
    __shared__ float Sn[512];                       // support norms slice, 2KB
    const int tid = threadIdx.x;
    const int w = tid >> 6, lane = tid & 63;
    const int q = lane >> 4, c16 = lane & 15;
    const int ss = blockIdx.x & 7;        // XCD %8 residency heuristic
    const int qt = blockIdx.x >> 3;

    // stage this slice's support norms once (epilogue reads LDS, not global)
    Sn[tid]       = norms[ss * 512 + tid];
    Sn[256 + tid] = norms[ss * 512 + 256 + tid];

    // resident Q fragments (A-layout m=c16): 64 VGPRs
    f16x8 qf[16];
    const f16* qb = E + (size_t)(N_SUP + qt * 64 + w * 16 + c16) * EMB + q * 8;
#pragma unroll
    for (int ks = 0; ks < 16; ++ks) qf[ks] = *(const f16x8*)(qb + ks * 32);
    float q2[4], mrow[4];
#pragma unroll
    for (int r = 0; r < 4; ++r) {
        q2[r]   = norms[N_SUP + qt * 64 + w * 16 + q * 4 + r];
        mrow[r] = manc[qt * 64 + w * 16 + q * 4 + r];
    }

    f32x4 accPL[4];
#pragma unroll
    for (int nb = 0; nb < 4; ++nb) accPL[nb] = (f32x4){0.f, 0.f, 0.f, 0.f};

    const f16* sb_base = Sb + (size_t)(ss * 512) * EMB;
    const int wslot = w * 256;            // wave's 256-slot region (x16B)

    // prologue: DMA tile 0 -> buf 0 (barrier also publishes Sn)
#pragma unroll
    for (int i = 0; i < 4; ++i)
        GLDS16(sb_base + (size_t)(wslot + i * 64 + lane) * 8,
               &Ss[0][(wslot + i * 64) * 8]);
    __syncthreads();

#pragma unroll 2
    for (int t = 0; t < 32; ++t) {
        const int cur = t & 1;
        if (t + 1 < 32) {
            const f16* gsrc = sb_base + (size_t)(t + 1) * 16 * EMB;
#pragma unroll
            for (int i = 0; i < 4; ++i)
                GLDS16(gsrc + (size_t)(wslot + i * 64 + lane) * 8,
                       &Ss[cur ^ 1][(wslot + i * 64) * 8]);
        }
        // odd tile: issue Lcs B-frag loads for this pair early (L2-hot;
        // latency covered by the QK MFMA chain below)
        f16x8 bl[4];
        if (t & 1) {
            const int ps0 = ss * 512 + (t >> 1) * 32;
#pragma unroll
            for (int nbc = 0; nbc < 4; ++nbc)
                bl[nbc] = *(const f16x8*)(Lcs + (size_t)(nbc * 16 + c16) * N_SUP + ps0 + q * 8);
        }

        // QK over full K=512 for 16 supports; wave 3 reads global (L2-hot),
        // waves 0-2 read LDS. Same index math (Ss is a linear tile copy).
        f32x4 a0 = (f32x4){0.f, 0.f, 0.f, 0.f};
        f32x4 a1 = (f32x4){0.f, 0.f, 0.f, 0.f};
        __builtin_amdgcn_s_setprio(1);
        if (w == 3) {
            const f16* bsrc = sb_base + (size_t)t * 16 * EMB;
            QK_BODY(bsrc, a0, a1)
        } else {
            const f16* bsrc = &Ss[cur][0];
            QK_BODY(bsrc, a0, a1)
        }
        __builtin_amdgcn_s_setprio(0);
        f32x4 accQK = a0 + a1;

        // epilogue: p = exp(m - d) -> Pt half (wave-private, DS pipe in-order)
        {
            const float s2 = Sn[t * 16 + c16];
            const int pcol = (t & 1) * 16 + c16;
#pragma unroll
            for (int r = 0; r < 4; ++r) {
                float d2 = fmaxf(q2[r] + s2 - 2.f * accQK[r], 0.f);
                float p = __expf(mrow[r] - __builtin_amdgcn_sqrtf(d2));
                p = fminf(p, 60000.f);     // f16-overflow guard
                Pt[w][q * 4 + r][pcol] = (f16)p;
            }
        }
        // PV: one K=32 chunk (two tiles' P) against 4 class-groups
        if (t & 1) {
            f16x8 af = *(const f16x8*)&Pt[w][c16][q * 8];
#pragma unroll
            for (int nbc = 0; nbc < 4; ++nbc)
                accPL[nbc] = __builtin_amdgcn_mfma_f32_16x16x32_f16(af, bl[nbc], accPL[nbc], 0, 0, 0);
        }

        __syncthreads();   // drains DMA(t+1) + syncs buffer swap
    }

#pragma unroll
    for (int nbc = 0; nbc < 4; ++nbc)
#pragma unroll
        for (int r = 0; r < 4; ++r)
            atomicAdd(&Num[(size_t)(qt * 64 + w * 16 + q * 4 + r) * NCLS + nbc * 16 + c16],
                      accPL[nbc][r]);
}

// ---- finalize: out[q][c] = Num[q][c] / rowsum(Num[q]) ----
__global__ __launch_bounds__(256) void finalize(const float* __restrict__ Num,
                                                float* __restrict__ out) {
    const int tid = threadIdx.x;
    const int w = tid >> 6, lane = tid & 63;
    const int qrow = blockIdx.x * 4 + w;
    float v = Num[(size_t)qrow * NCLS + lane];
    float s = v;
    s += __shfl_xor(s, 1);  s += __shfl_xor(s, 2);  s += __shfl_xor(s, 4);
    s += __shfl_xor(s, 8);  s += __shfl_xor(s, 16); s += __shfl_xor(s, 32);
    out[(size_t)qrow * NCLS + lane] = v / s;
}

extern "C" void kernel_launch(void* const* d_in, const int* in_sizes, int n_in,
                              void* d_out, int out_size, void* d_ws, size_t ws_size,
                              hipStream_t stream) {
    (void)in_sizes; (void)n_in; (void)out_size; (void)ws_size;
    const float* sup  = (const float*)d_in[0];
    const float* qry  = (const float*)d_in[1];
    const float* lab  = (const float*)d_in[2];
    const float* Wenc = (const float*)d_in[3];
    const float* benc = (const float*)d_in[4];
    float* out = (float*)d_out;

    char* ws = (char*)d_ws;
    size_t off = 0;
    f16* Wb = (f16*)(ws + off);        off += (size_t)NCHUNK * 32 * 64 * 8 * 2; // 819200
    f16* E  = (f16*)(ws + off);        off += (size_t)M_TOT * EMB * 2;          // 12582912
    f16* Sb = (f16*)(ws + off);        off += (size_t)N_SUP * EMB * 2;          // 4194304
    int* lbl = (int*)(ws + off);       off += (size_t)N_SUP * 4;                // 16384
    f16* Lcs = (f16*)(ws + off);       off += (size_t)NCLS * N_SUP * 2;         // 524288
    float* manc = (float*)(ws + off);  off += (size_t)N_QRY * 4;                // 32768
    float* norms = (float*)(ws + off); off += (size_t)M_TOT * 4;                // 49152
    float* Num = (float*)(ws + off);   off += (size_t)N_QRY * NCLS * 4;         // 2097152

    // norms and Num adjacent: one memset
    hipMemsetAsync(norms, 0, (size_t)M_TOT * 4 + (size_t)N_QRY * NCLS * 4, stream);

    pre_enc<<<1224, 256, 0, stream>>>(Wenc, lab, Wb, lbl);
    encode<<<M_TOT / 32 * 2, 256, 0, stream>>>(sup, qry, Wb, benc, E, norms);
    post_enc<<<4096, 256, 0, stream>>>(E, norms, lbl, Sb, Lcs, manc);
    attn<<<N_QRY / 64 * 8, 256, 0, stream>>>(E, norms, manc, Lcs, Sb, Num);
    finalize<<<N_QRY / 4, 256, 0, stream>>>(Num, out);
}

// Round 5
// 205.107 us; speedup vs baseline: 2.5965x; 2.5965x over previous
//
#include <hip/hip_runtime.h>

#define N_SUP 4096
#define N_QRY 8192
#define IN_DIM 784
#define EMB 512
#define NCLS 64
#define M_TOT (N_SUP + N_QRY)
#define NCHUNK 25   // ceil(784/32)
#define XCH 13      // ceil(784/64)

typedef _Float16 f16;
typedef _Float16 f16x8 __attribute__((ext_vector_type(8)));
typedef float f32x4 __attribute__((ext_vector_type(4)));

// async global->LDS, 16B per lane. LDS dest is wave-uniform base + lane*16.
#define GLDS16(gp, lp)                                                        \
    __builtin_amdgcn_global_load_lds(                                         \
        (const __attribute__((address_space(1))) void*)(gp),                  \
        (__attribute__((address_space(3))) void*)(lp), 16, 0, 0)

// load 8 consecutive fp32 and convert to f16x8
static __device__ __forceinline__ f16x8 cvt8(const float* p) {
    float4 a = *(const float4*)p;
    float4 b = *(const float4*)(p + 4);
    f16x8 v;
    v[0] = (f16)a.x; v[1] = (f16)a.y; v[2] = (f16)a.z; v[3] = (f16)a.w;
    v[4] = (f16)b.x; v[5] = (f16)b.y; v[6] = (f16)b.z; v[7] = (f16)b.w;
    return v;
}

// ---- fused prep: blocks [0,200) = Wb repack, [200,1224) = label argmax ----
__global__ __launch_bounds__(256) void pre_enc(const float* __restrict__ W,
                                               const float* __restrict__ lab,
                                               f16* __restrict__ Wb,
                                               int* __restrict__ lbl) {
    if (blockIdx.x < 200) {
        int g = blockIdx.x * 256 + threadIdx.x;      // 51200 frag-lanes
        if (g >= NCHUNK * 32 * 64) return;
        int chunk = g >> 11;
        int rem = g & 2047;
        int nbg = rem >> 6, lane = rem & 63;
        int n = nbg * 16 + (lane & 15);
        int kbase = chunk * 32 + (lane >> 4) * 8;
        f16x8 v;
#pragma unroll
        for (int j = 0; j < 8; ++j) {
            int k = kbase + j;
            v[j] = (k < IN_DIM) ? (f16)W[(size_t)k * EMB + n] : (f16)0.f;
        }
        *(f16x8*)(Wb + (size_t)g * 8) = v;
    } else {
        const int w = threadIdx.x >> 6, lane = threadIdx.x & 63;
        const int s = (blockIdx.x - 200) * 4 + w;
        float v = lab[(size_t)s * NCLS + lane];
        int c = lane;
#pragma unroll
        for (int off = 1; off < 64; off <<= 1) {
            float v2 = __shfl_xor(v, off);
            int c2 = __shfl_xor(c, off);
            if (v2 > v || (v2 == v && c2 < c)) { v = v2; c = c2; }
        }
        if (lane == 0) lbl[s] = c;
    }
}

// ---- encode: 32 rows x 256 cols per block, grid 768 (3 blocks/CU).
// Support blocks also emit the bank-swizzled Sb copy directly (same values,
// scalar form of prep_sb's XOR) -> no separate Sb pass needed. ----
__global__ __launch_bounds__(256) void encode(
    const float* __restrict__ sup, const float* __restrict__ qry,
    const f16* __restrict__ Wb, const float* __restrict__ bias,
    f16* __restrict__ E, f16* __restrict__ Sb, float* __restrict__ norms)
{
    __shared__ __align__(16) f16 Xs[32][72];
    const int tid = threadIdx.x;
    const int w = tid >> 6, lane = tid & 63;
    const int q = lane >> 4, c16 = lane & 15;
    const int mb = blockIdx.x >> 1;
    const int ch = blockIdx.x & 1;
    const int m0 = mb * 32;
    const int rbase = (w & 1) * 16;
    const int nbg0 = ch * 16 + (w >> 1) * 8;
    const int cbase = nbg0 * 16;

    f32x4 acc[8];
#pragma unroll
    for (int nb = 0; nb < 8; ++nb) acc[nb] = (f32x4){0.f, 0.f, 0.f, 0.f};

    const int sr = tid >> 3;
    const int sq = tid & 7;
    const float* xrow;
    {
        int gr = m0 + sr;
        xrow = (gr < N_SUP) ? sup + (size_t)gr * IN_DIM
                            : qry + (size_t)(gr - N_SUP) * IN_DIM;
    }

    f16x8 xg = cvt8(xrow + sq * 8);

    for (int c = 0; c < XCH; ++c) {
        __syncthreads();
        *(f16x8*)&Xs[sr][sq * 8] = xg;
        __syncthreads();
        if (c + 1 < XCH) {
            int k = (c + 1) * 64 + sq * 8;
            xg = (k + 8 <= IN_DIM) ? cvt8(xrow + k) : (f16x8){0,0,0,0,0,0,0,0};
        }
#pragma unroll
        for (int kc = 0; kc < 2; ++kc) {
            int c32 = c * 2 + kc;
            if (c32 >= NCHUNK) break;
            f16x8 a = *(const f16x8*)&Xs[rbase + c16][kc * 32 + q * 8];
            const f16* wb = Wb + ((size_t)(c32 * 32 + nbg0) * 64 + lane) * 8;
#pragma unroll
            for (int nb = 0; nb < 8; ++nb) {
                f16x8 b = *(const f16x8*)(wb + (size_t)nb * 512);
                acc[nb] = __builtin_amdgcn_mfma_f32_16x16x32_f16(a, b, acc[nb], 0, 0, 0);
            }
        }
    }

    const bool isSup = (m0 < N_SUP);   // block-uniform: rows m0..m0+31
    float nrm[4] = {0.f, 0.f, 0.f, 0.f};
#pragma unroll
    for (int nb = 0; nb < 8; ++nb) {
        int col = cbase + nb * 16 + c16;
        float bv = bias[col];
#pragma unroll
        for (int r = 0; r < 4; ++r) {
            int row = m0 + rbase + q * 4 + r;
            float v = acc[nb][r] + bv;
            f16 h = (f16)v;
            E[(size_t)row * EMB + col] = h;
            if (isSup) {
                int dst = (((col >> 3) ^ (row & 15)) << 3) | (col & 7);
                Sb[(size_t)row * EMB + dst] = h;
            }
            nrm[r] += v * v;
        }
    }
#pragma unroll
    for (int r = 0; r < 4; ++r) {
        float v = nrm[r];
        v += __shfl_xor(v, 1); v += __shfl_xor(v, 2);
        v += __shfl_xor(v, 4); v += __shfl_xor(v, 8);
        if (c16 == 0) atomicAdd(&norms[m0 + rbase + q * 4 + r], v);
    }
}

// ---- fused post-encode: [0,2048) anchor, [2048,3072) Lcs transpose ----
__global__ __launch_bounds__(256) void post_enc(
    const f16* __restrict__ E, const float* __restrict__ norms,
    const int* __restrict__ lbl, f16* __restrict__ Lcs,
    float* __restrict__ manc)
{
    const int b = blockIdx.x;
    if (b < 2048) {
        const int w = threadIdx.x >> 6, lane = threadIdx.x & 63;
        const int qrow = b * 4 + w;
        f16x8 qv = *(const f16x8*)(E + (size_t)(N_SUP + qrow) * EMB + lane * 8);
        f16x8 sv = *(const f16x8*)(E + lane * 8);
        float dot = 0.f;
#pragma unroll
        for (int j = 0; j < 8; ++j) dot += (float)qv[j] * (float)sv[j];
        dot += __shfl_xor(dot, 1);  dot += __shfl_xor(dot, 2);
        dot += __shfl_xor(dot, 4);  dot += __shfl_xor(dot, 8);
        dot += __shfl_xor(dot, 16); dot += __shfl_xor(dot, 32);
        if (lane == 0) {
            float d2 = fmaxf(norms[N_SUP + qrow] + norms[0] - 2.f * dot, 0.f);
            manc[qrow] = sqrtf(d2);
        }
    } else {
        int idx = (b - 2048) * 256 + threadIdx.x;
        int c = idx >> 12, s = idx & (N_SUP - 1);
        Lcs[idx] = (lbl[s] == c) ? (f16)1.f : (f16)0.f;
    }
}

// ---- attn v6: exact v3 structure (best: 86.4us) + dual-chain QK (two
// independent 8-MFMA chains halve the dependent-latency per tile) +
// setprio(1) around the QK cluster (m191: +4-7% on attn). ALL B-frag
// reads from LDS — the v5 global-read split thrashed L2->HBM (361MB
// FETCH); reverted. ----
__global__ __launch_bounds__(256, 3) void attn(
    const f16* __restrict__ E, const float* __restrict__ norms,
    const float* __restrict__ manc, const f16* __restrict__ Lcs,
    const f16* __restrict__ Sb, float* __restrict__ Num)
{
    __shared__ __align__(16) f16 Ss[2][16 * EMB];   // 2 x 16KB
    __shared__ __align__(16) f16 Pt[4][16][40];     // per-wave P transpose, 5KB
    __shared__ float Sn[512];                       // support norms slice, 2KB
    const int tid = threadIdx.x;
    const int w = tid >> 6, lane = tid & 63;
    const int q = lane >> 4, c16 = lane & 15;
    const int ss = blockIdx.x & 7;        // XCD %8 residency heuristic
    const int qt = blockIdx.x >> 3;

    // stage this slice's support norms once (epilogue reads LDS, not global)
    Sn[tid]       = norms[ss * 512 + tid];
    Sn[256 + tid] = norms[ss * 512 + 256 + tid];

    // resident Q fragments (A-layout m=c16): 64 VGPRs
    f16x8 qf[16];
    const f16* qb = E + (size_t)(N_SUP + qt * 64 + w * 16 + c16) * EMB + q * 8;
#pragma unroll
    for (int ks = 0; ks < 16; ++ks) qf[ks] = *(const f16x8*)(qb + ks * 32);
    float q2[4], mrow[4];
#pragma unroll
    for (int r = 0; r < 4; ++r) {
        q2[r]   = norms[N_SUP + qt * 64 + w * 16 + q * 4 + r];
        mrow[r] = manc[qt * 64 + w * 16 + q * 4 + r];
    }

    f32x4 accPL[4];
#pragma unroll
    for (int nb = 0; nb < 4; ++nb) accPL[nb] = (f32x4){0.f, 0.f, 0.f, 0.f};

    const f16* sb_base = Sb + (size_t)(ss * 512) * EMB;
    const int wslot = w * 256;            // wave's 256-slot region (x16B)

    // prologue: DMA tile 0 -> buf 0 (barrier also publishes Sn)
#pragma unroll
    for (int i = 0; i < 4; ++i)
        GLDS16(sb_base + (size_t)(wslot + i * 64 + lane) * 8,
               &Ss[0][(wslot + i * 64) * 8]);
    __syncthreads();

#pragma unroll 2
    for (int t = 0; t < 32; ++t) {
        const int cur = t & 1;
        if (t + 1 < 32) {
            const f16* gsrc = sb_base + (size_t)(t + 1) * 16 * EMB;
#pragma unroll
            for (int i = 0; i < 4; ++i)
                GLDS16(gsrc + (size_t)(wslot + i * 64 + lane) * 8,
                       &Ss[cur ^ 1][(wslot + i * 64) * 8]);
        }
        // odd tile: issue Lcs B-frag loads for this pair early (L2-hot;
        // latency covered by the QK MFMA chain below)
        f16x8 bl[4];
        if (t & 1) {
            const int ps0 = ss * 512 + (t >> 1) * 32;
#pragma unroll
            for (int nbc = 0; nbc < 4; ++nbc)
                bl[nbc] = *(const f16x8*)(Lcs + (size_t)(nbc * 16 + c16) * N_SUP + ps0 + q * 8);
        }

        // QK over full K=512 for 16 supports: two independent MFMA chains
        f32x4 a0 = (f32x4){0.f, 0.f, 0.f, 0.f};
        f32x4 a1 = (f32x4){0.f, 0.f, 0.f, 0.f};
        __builtin_amdgcn_s_setprio(1);
#pragma unroll
        for (int kc = 0; kc < 4; ++kc) {
#pragma unroll
            for (int ksl = 0; ksl < 4; ++ksl) {
                const int lg = kc * 16 + ksl * 4 + q;
                f16x8 b = *(const f16x8*)&Ss[cur][c16 * EMB + ((lg ^ c16) * 8)];
                if (ksl & 1)
                    a1 = __builtin_amdgcn_mfma_f32_16x16x32_f16(qf[kc * 4 + ksl], b, a1, 0, 0, 0);
                else
                    a0 = __builtin_amdgcn_mfma_f32_16x16x32_f16(qf[kc * 4 + ksl], b, a0, 0, 0, 0);
            }
        }
        __builtin_amdgcn_s_setprio(0);
        f32x4 accQK = a0 + a1;

        // epilogue: p = exp(m - d) -> Pt half (wave-private, DS pipe in-order)
        {
            const float s2 = Sn[t * 16 + c16];
            const int pcol = (t & 1) * 16 + c16;
#pragma unroll
            for (int r = 0; r < 4; ++r) {
                float d2 = fmaxf(q2[r] + s2 - 2.f * accQK[r], 0.f);
                float p = __expf(mrow[r] - __builtin_amdgcn_sqrtf(d2));
                p = fminf(p, 60000.f);     // f16-overflow guard
                Pt[w][q * 4 + r][pcol] = (f16)p;
            }
        }
        // PV: one K=32 chunk (two tiles' P) against 4 class-groups
        if (t & 1) {
            f16x8 af = *(const f16x8*)&Pt[w][c16][q * 8];
#pragma unroll
            for (int nbc = 0; nbc < 4; ++nbc)
                accPL[nbc] = __builtin_amdgcn_mfma_f32_16x16x32_f16(af, bl[nbc], accPL[nbc], 0, 0, 0);
        }

        __syncthreads();   // drains DMA(t+1) + syncs buffer swap
    }

#pragma unroll
    for (int nbc = 0; nbc < 4; ++nbc)
#pragma unroll
        for (int r = 0; r < 4; ++r)
            atomicAdd(&Num[(size_t)(qt * 64 + w * 16 + q * 4 + r) * NCLS + nbc * 16 + c16],
                      accPL[nbc][r]);
}

// ---- finalize: out[q][c] = Num[q][c] / rowsum(Num[q]) ----
__global__ __launch_bounds__(256) void finalize(const float* __restrict__ Num,
                                                float* __restrict__ out) {
    const int tid = threadIdx.x;
    const int w = tid >> 6, lane = tid & 63;
    const int qrow = blockIdx.x * 4 + w;
    float v = Num[(size_t)qrow * NCLS + lane];
    float s = v;
    s += __shfl_xor(s, 1);  s += __shfl_xor(s, 2);  s += __shfl_xor(s, 4);
    s += __shfl_xor(s, 8);  s += __shfl_xor(s, 16); s += __shfl_xor(s, 32);
    out[(size_t)qrow * NCLS + lane] = v / s;
}

extern "C" void kernel_launch(void* const* d_in, const int* in_sizes, int n_in,
                              void* d_out, int out_size, void* d_ws, size_t ws_size,
                              hipStream_t stream) {
    (void)in_sizes; (void)n_in; (void)out_size; (void)ws_size;
    const float* sup  = (const float*)d_in[0];
    const float* qry  = (const float*)d_in[1];
    const float* lab  = (const float*)d_in[2];
    const float* Wenc = (const float*)d_in[3];
    const float* benc = (const float*)d_in[4];
    float* out = (float*)d_out;

    char* ws = (char*)d_ws;
    size_t off = 0;
    f16* Wb = (f16*)(ws + off);        off += (size_t)NCHUNK * 32 * 64 * 8 * 2; // 819200
    f16* E  = (f16*)(ws + off);        off += (size_t)M_TOT * EMB * 2;          // 12582912
    f16* Sb = (f16*)(ws + off);        off += (size_t)N_SUP * EMB * 2;          // 4194304
    int* lbl = (int*)(ws + off);       off += (size_t)N_SUP * 4;                // 16384
    f16* Lcs = (f16*)(ws + off);       off += (size_t)NCLS * N_SUP * 2;         // 524288
    float* manc = (float*)(ws + off);  off += (size_t)N_QRY * 4;                // 32768
    float* norms = (float*)(ws + off); off += (size_t)M_TOT * 4;                // 49152
    float* Num = (float*)(ws + off);   off += (size_t)N_QRY * NCLS * 4;         // 2097152

    // norms and Num adjacent: one memset
    hipMemsetAsync(norms, 0, (size_t)M_TOT * 4 + (size_t)N_QRY * NCLS * 4, stream);

    pre_enc<<<1224, 256, 0, stream>>>(Wenc, lab, Wb, lbl);
    encode<<<M_TOT / 32 * 2, 256, 0, stream>>>(sup, qry, Wb, benc, E, Sb, norms);
    post_enc<<<3072, 256, 0, stream>>>(E, norms, lbl, Lcs, manc);
    attn<<<N_QRY / 64 * 8, 256, 0, stream>>>(E, norms, manc, Lcs, Sb, Num);
    finalize<<<N_QRY / 4, 256, 0, stream>>>(Num, out);
}

// Round 6
// 201.695 us; speedup vs baseline: 2.6404x; 1.0169x over previous
//
#include <hip/hip_runtime.h>

#define N_SUP 4096
#define N_QRY 8192
#define IN_DIM 784
#define EMB 512
#define NCLS 64
#define M_TOT (N_SUP + N_QRY)
#define NCHUNK 25   // ceil(784/32)
#define XCH 13      // ceil(784/64)

typedef _Float16 f16;
typedef _Float16 f16x8 __attribute__((ext_vector_type(8)));
typedef float f32x4 __attribute__((ext_vector_type(4)));

// async global->LDS, 16B per lane. LDS dest is wave-uniform base + lane*16.
#define GLDS16(gp, lp)                                                        \
    __builtin_amdgcn_global_load_lds(                                         \
        (const __attribute__((address_space(1))) void*)(gp),                  \
        (__attribute__((address_space(3))) void*)(lp), 16, 0, 0)

// load 8 consecutive fp32 and convert to f16x8
static __device__ __forceinline__ f16x8 cvt8(const float* p) {
    float4 a = *(const float4*)p;
    float4 b = *(const float4*)(p + 4);
    f16x8 v;
    v[0] = (f16)a.x; v[1] = (f16)a.y; v[2] = (f16)a.z; v[3] = (f16)a.w;
    v[4] = (f16)b.x; v[5] = (f16)b.y; v[6] = (f16)b.z; v[7] = (f16)b.w;
    return v;
}

// ---- fused prep: blocks [0,200) = Wb repack, [200,1224) = label argmax ----
__global__ __launch_bounds__(256) void pre_enc(const float* __restrict__ W,
                                               const float* __restrict__ lab,
                                               f16* __restrict__ Wb,
                                               int* __restrict__ lbl) {
    if (blockIdx.x < 200) {
        int g = blockIdx.x * 256 + threadIdx.x;      // 51200 frag-lanes
        if (g >= NCHUNK * 32 * 64) return;
        int chunk = g >> 11;
        int rem = g & 2047;
        int nbg = rem >> 6, lane = rem & 63;
        int n = nbg * 16 + (lane & 15);
        int kbase = chunk * 32 + (lane >> 4) * 8;
        f16x8 v;
#pragma unroll
        for (int j = 0; j < 8; ++j) {
            int k = kbase + j;
            v[j] = (k < IN_DIM) ? (f16)W[(size_t)k * EMB + n] : (f16)0.f;
        }
        *(f16x8*)(Wb + (size_t)g * 8) = v;
    } else {
        const int w = threadIdx.x >> 6, lane = threadIdx.x & 63;
        const int s = (blockIdx.x - 200) * 4 + w;
        float v = lab[(size_t)s * NCLS + lane];
        int c = lane;
#pragma unroll
        for (int off = 1; off < 64; off <<= 1) {
            float v2 = __shfl_xor(v, off);
            int c2 = __shfl_xor(c, off);
            if (v2 > v || (v2 == v && c2 < c)) { v = v2; c = c2; }
        }
        if (lane == 0) lbl[s] = c;
    }
}

// ---- encode: 32 rows x 256 cols per block, grid 768 (3 blocks/CU). ----
__global__ __launch_bounds__(256) void encode(
    const float* __restrict__ sup, const float* __restrict__ qry,
    const f16* __restrict__ Wb, const float* __restrict__ bias,
    f16* __restrict__ E, float* __restrict__ norms)
{
    __shared__ __align__(16) f16 Xs[32][72];
    const int tid = threadIdx.x;
    const int w = tid >> 6, lane = tid & 63;
    const int q = lane >> 4, c16 = lane & 15;
    const int mb = blockIdx.x >> 1;
    const int ch = blockIdx.x & 1;
    const int m0 = mb * 32;
    const int rbase = (w & 1) * 16;
    const int nbg0 = ch * 16 + (w >> 1) * 8;
    const int cbase = nbg0 * 16;

    f32x4 acc[8];
#pragma unroll
    for (int nb = 0; nb < 8; ++nb) acc[nb] = (f32x4){0.f, 0.f, 0.f, 0.f};

    const int sr = tid >> 3;
    const int sq = tid & 7;
    const float* xrow;
    {
        int gr = m0 + sr;
        xrow = (gr < N_SUP) ? sup + (size_t)gr * IN_DIM
                            : qry + (size_t)(gr - N_SUP) * IN_DIM;
    }

    f16x8 xg = cvt8(xrow + sq * 8);

    for (int c = 0; c < XCH; ++c) {
        __syncthreads();
        *(f16x8*)&Xs[sr][sq * 8] = xg;
        __syncthreads();
        if (c + 1 < XCH) {
            int k = (c + 1) * 64 + sq * 8;
            xg = (k + 8 <= IN_DIM) ? cvt8(xrow + k) : (f16x8){0,0,0,0,0,0,0,0};
        }
#pragma unroll
        for (int kc = 0; kc < 2; ++kc) {
            int c32 = c * 2 + kc;
            if (c32 >= NCHUNK) break;
            f16x8 a = *(const f16x8*)&Xs[rbase + c16][kc * 32 + q * 8];
            const f16* wb = Wb + ((size_t)(c32 * 32 + nbg0) * 64 + lane) * 8;
#pragma unroll
            for (int nb = 0; nb < 8; ++nb) {
                f16x8 b = *(const f16x8*)(wb + (size_t)nb * 512);
                acc[nb] = __builtin_amdgcn_mfma_f32_16x16x32_f16(a, b, acc[nb], 0, 0, 0);
            }
        }
    }

    float nrm[4] = {0.f, 0.f, 0.f, 0.f};
#pragma unroll
    for (int nb = 0; nb < 8; ++nb) {
        int col = cbase + nb * 16 + c16;
        float bv = bias[col];
#pragma unroll
        for (int r = 0; r < 4; ++r) {
            int row = m0 + rbase + q * 4 + r;
            float v = acc[nb][r] + bv;
            E[(size_t)row * EMB + col] = (f16)v;
            nrm[r] += v * v;
        }
    }
#pragma unroll
    for (int r = 0; r < 4; ++r) {
        float v = nrm[r];
        v += __shfl_xor(v, 1); v += __shfl_xor(v, 2);
        v += __shfl_xor(v, 4); v += __shfl_xor(v, 8);
        if (c16 == 0) atomicAdd(&norms[m0 + rbase + q * 4 + r], v);
    }
}

// ---- fused post-encode: [0,1024) Sb swizzle, [1024,3072) anchor,
//      [3072,4096) Lcs one-hot transpose ----
__global__ __launch_bounds__(256) void post_enc(
    const f16* __restrict__ E, const float* __restrict__ norms,
    const int* __restrict__ lbl, f16* __restrict__ Sb,
    f16* __restrict__ Lcs, float* __restrict__ manc)
{
    const int b = blockIdx.x;
    if (b < 1024) {
        int g = b * 256 + threadIdx.x;   // 262144 groups of 8 f16
        int s = g >> 6, lg = g & 63;
        f16x8 v = *(const f16x8*)(E + (size_t)s * EMB + lg * 8);
        *(f16x8*)(Sb + (size_t)s * EMB + ((lg ^ (s & 15)) * 8)) = v;
    } else if (b < 3072) {
        const int w = threadIdx.x >> 6, lane = threadIdx.x & 63;
        const int qrow = (b - 1024) * 4 + w;
        f16x8 qv = *(const f16x8*)(E + (size_t)(N_SUP + qrow) * EMB + lane * 8);
        f16x8 sv = *(const f16x8*)(E + lane * 8);
        float dot = 0.f;
#pragma unroll
        for (int j = 0; j < 8; ++j) dot += (float)qv[j] * (float)sv[j];
        dot += __shfl_xor(dot, 1);  dot += __shfl_xor(dot, 2);
        dot += __shfl_xor(dot, 4);  dot += __shfl_xor(dot, 8);
        dot += __shfl_xor(dot, 16); dot += __shfl_xor(dot, 32);
        if (lane == 0) {
            float d2 = fmaxf(norms[N_SUP + qrow] + norms[0] - 2.f * dot, 0.f);
            manc[qrow] = sqrtf(d2);
        }
    } else {
        int idx = (b - 3072) * 256 + threadIdx.x;
        int c = idx >> 12, s = idx & (N_SUP - 1);
        Lcs[idx] = (lbl[s] == c) ? (f16)1.f : (f16)0.f;
    }
}

// ---- attn v7: A-reuse restructure. 128-thread blocks (2 waves); each wave
// owns 32 q-rows (qf[32] resident, 128 VGPR) and does 2 MFMAs per B-frag
// read. Rationale: v3's DS pipe was the tallest pole (47% busy; 1 ds_read
// per MFMA, 4-wave broadcast of each S-tile). This halves LDS bytes/FLOP:
// same 16 reads/tile/wave, 2x the output. LDS unchanged (39936B -> 4
// blocks/CU = 8 waves/CU = 2/SIMD, which ~215 VGPR fits exactly). ----
__global__ __launch_bounds__(128, 2) void attn(
    const f16* __restrict__ E, const float* __restrict__ norms,
    const float* __restrict__ manc, const f16* __restrict__ Lcs,
    const f16* __restrict__ Sb, float* __restrict__ Num)
{
    __shared__ __align__(16) f16 Ss[2][16 * EMB];   // 2 x 16KB
    __shared__ __align__(16) f16 Pt[2][32][40];     // per-wave P transpose, 5KB
    __shared__ float Sn[512];                       // support norms slice, 2KB
    const int tid = threadIdx.x;
    const int w = tid >> 6, lane = tid & 63;
    const int q = lane >> 4, c16 = lane & 15;
    const int ss = blockIdx.x & 7;        // XCD %8 residency heuristic
    const int qt = blockIdx.x >> 3;

    // stage this slice's support norms once (epilogue reads LDS, not global)
    Sn[tid]       = norms[ss * 512 + tid];
    Sn[128 + tid] = norms[ss * 512 + 128 + tid];
    Sn[256 + tid] = norms[ss * 512 + 256 + tid];
    Sn[384 + tid] = norms[ss * 512 + 384 + tid];

    // resident Q fragments for 32 rows (A-layout m=c16): 128 VGPRs
    f16x8 qf[32];
    const f16* qb = E + (size_t)(N_SUP + qt * 64 + w * 32 + c16) * EMB + q * 8;
#pragma unroll
    for (int rg = 0; rg < 2; ++rg)
#pragma unroll
        for (int ks = 0; ks < 16; ++ks)
            qf[rg * 16 + ks] = *(const f16x8*)(qb + (size_t)rg * 16 * EMB + ks * 32);
    float q2[8], mrow[8];
#pragma unroll
    for (int rg = 0; rg < 2; ++rg)
#pragma unroll
        for (int r = 0; r < 4; ++r) {
            int row = qt * 64 + w * 32 + rg * 16 + q * 4 + r;
            q2[rg * 4 + r]   = norms[N_SUP + row];
            mrow[rg * 4 + r] = manc[row];
        }

    f32x4 accPL[2][4];
#pragma unroll
    for (int rg = 0; rg < 2; ++rg)
#pragma unroll
        for (int nb = 0; nb < 4; ++nb) accPL[rg][nb] = (f32x4){0.f, 0.f, 0.f, 0.f};

    const f16* sb_base = Sb + (size_t)(ss * 512) * EMB;
    const int wslot = w * 512;            // wave's 512-slot region (x16B)

    // prologue: DMA tile 0 -> buf 0 (barrier also publishes Sn)
#pragma unroll
    for (int i = 0; i < 8; ++i)
        GLDS16(sb_base + (size_t)(wslot + i * 64 + lane) * 8,
               &Ss[0][(wslot + i * 64) * 8]);
    __syncthreads();

#pragma unroll 2
    for (int t = 0; t < 32; ++t) {
        const int cur = t & 1;
        if (t + 1 < 32) {
            const f16* gsrc = sb_base + (size_t)(t + 1) * 16 * EMB;
#pragma unroll
            for (int i = 0; i < 8; ++i)
                GLDS16(gsrc + (size_t)(wslot + i * 64 + lane) * 8,
                       &Ss[cur ^ 1][(wslot + i * 64) * 8]);
        }
        // odd tile: issue Lcs B-frag loads for this pair early (L2-hot;
        // latency covered by the QK MFMA chain below)
        f16x8 bl[4];
        if (t & 1) {
            const int ps0 = ss * 512 + (t >> 1) * 32;
#pragma unroll
            for (int nbc = 0; nbc < 4; ++nbc)
                bl[nbc] = *(const f16x8*)(Lcs + (size_t)(nbc * 16 + c16) * N_SUP + ps0 + q * 8);
        }

        // QK over full K=512 for 16 supports x 32 q-rows: each B-frag read
        // feeds 2 MFMAs (row-groups) -> half the DS traffic per FLOP.
        f32x4 a0 = (f32x4){0.f, 0.f, 0.f, 0.f};
        f32x4 a1 = (f32x4){0.f, 0.f, 0.f, 0.f};
#pragma unroll
        for (int kc = 0; kc < 4; ++kc) {
#pragma unroll
            for (int ksl = 0; ksl < 4; ++ksl) {
                const int lg = kc * 16 + ksl * 4 + q;
                f16x8 b = *(const f16x8*)&Ss[cur][c16 * EMB + ((lg ^ c16) * 8)];
                a0 = __builtin_amdgcn_mfma_f32_16x16x32_f16(qf[kc * 4 + ksl], b, a0, 0, 0, 0);
                a1 = __builtin_amdgcn_mfma_f32_16x16x32_f16(qf[16 + kc * 4 + ksl], b, a1, 0, 0, 0);
            }
        }

        // epilogue: p = exp(m - d) -> Pt half (wave-private, DS pipe in-order)
        {
            const float s2 = Sn[t * 16 + c16];
            const int pcol = (t & 1) * 16 + c16;
#pragma unroll
            for (int r = 0; r < 4; ++r) {
                float d2 = fmaxf(q2[r] + s2 - 2.f * a0[r], 0.f);
                float p = __expf(mrow[r] - __builtin_amdgcn_sqrtf(d2));
                Pt[w][q * 4 + r][pcol] = (f16)fminf(p, 60000.f);
            }
#pragma unroll
            for (int r = 0; r < 4; ++r) {
                float d2 = fmaxf(q2[4 + r] + s2 - 2.f * a1[r], 0.f);
                float p = __expf(mrow[4 + r] - __builtin_amdgcn_sqrtf(d2));
                Pt[w][16 + q * 4 + r][pcol] = (f16)fminf(p, 60000.f);
            }
        }
        // PV: one K=32 chunk (two tiles' P) against 4 class-groups, both
        // row-groups share the bl[] fragments.
        if (t & 1) {
            f16x8 af0 = *(const f16x8*)&Pt[w][c16][q * 8];
            f16x8 af1 = *(const f16x8*)&Pt[w][16 + c16][q * 8];
#pragma unroll
            for (int nbc = 0; nbc < 4; ++nbc) {
                accPL[0][nbc] = __builtin_amdgcn_mfma_f32_16x16x32_f16(af0, bl[nbc], accPL[0][nbc], 0, 0, 0);
                accPL[1][nbc] = __builtin_amdgcn_mfma_f32_16x16x32_f16(af1, bl[nbc], accPL[1][nbc], 0, 0, 0);
            }
        }

        __syncthreads();   // drains DMA(t+1) + syncs buffer swap
    }

#pragma unroll
    for (int rg = 0; rg < 2; ++rg)
#pragma unroll
        for (int nbc = 0; nbc < 4; ++nbc)
#pragma unroll
            for (int r = 0; r < 4; ++r)
                atomicAdd(&Num[(size_t)(qt * 64 + w * 32 + rg * 16 + q * 4 + r) * NCLS + nbc * 16 + c16],
                          accPL[rg][nbc][r]);
}

// ---- finalize: out[q][c] = Num[q][c] / rowsum(Num[q]) ----
__global__ __launch_bounds__(256) void finalize(const float* __restrict__ Num,
                                                float* __restrict__ out) {
    const int tid = threadIdx.x;
    const int w = tid >> 6, lane = tid & 63;
    const int qrow = blockIdx.x * 4 + w;
    float v = Num[(size_t)qrow * NCLS + lane];
    float s = v;
    s += __shfl_xor(s, 1);  s += __shfl_xor(s, 2);  s += __shfl_xor(s, 4);
    s += __shfl_xor(s, 8);  s += __shfl_xor(s, 16); s += __shfl_xor(s, 32);
    out[(size_t)qrow * NCLS + lane] = v / s;
}

extern "C" void kernel_launch(void* const* d_in, const int* in_sizes, int n_in,
                              void* d_out, int out_size, void* d_ws, size_t ws_size,
                              hipStream_t stream) {
    (void)in_sizes; (void)n_in; (void)out_size; (void)ws_size;
    const float* sup  = (const float*)d_in[0];
    const float* qry  = (const float*)d_in[1];
    const float* lab  = (const float*)d_in[2];
    const float* Wenc = (const float*)d_in[3];
    const float* benc = (const float*)d_in[4];
    float* out = (float*)d_out;

    char* ws = (char*)d_ws;
    size_t off = 0;
    f16* Wb = (f16*)(ws + off);        off += (size_t)NCHUNK * 32 * 64 * 8 * 2; // 819200
    f16* E  = (f16*)(ws + off);        off += (size_t)M_TOT * EMB * 2;          // 12582912
    f16* Sb = (f16*)(ws + off);        off += (size_t)N_SUP * EMB * 2;          // 4194304
    int* lbl = (int*)(ws + off);       off += (size_t)N_SUP * 4;                // 16384
    f16* Lcs = (f16*)(ws + off);       off += (size_t)NCLS * N_SUP * 2;         // 524288
    float* manc = (float*)(ws + off);  off += (size_t)N_QRY * 4;                // 32768
    float* norms = (float*)(ws + off); off += (size_t)M_TOT * 4;                // 49152
    float* Num = (float*)(ws + off);   off += (size_t)N_QRY * NCLS * 4;         // 2097152

    // norms and Num adjacent: one memset
    hipMemsetAsync(norms, 0, (size_t)M_TOT * 4 + (size_t)N_QRY * NCLS * 4, stream);

    pre_enc<<<1224, 256, 0, stream>>>(Wenc, lab, Wb, lbl);
    encode<<<M_TOT / 32 * 2, 256, 0, stream>>>(sup, qry, Wb, benc, E, norms);
    post_enc<<<4096, 256, 0, stream>>>(E, norms, lbl, Sb, Lcs, manc);
    attn<<<N_QRY / 64 * 8, 128, 0, stream>>>(E, norms, manc, Lcs, Sb, Num);
    finalize<<<N_QRY / 4, 256, 0, stream>>>(Num, out);
}

// Round 7
// 198.890 us; speedup vs baseline: 2.6777x; 1.0141x over previous
//
#include <hip/hip_runtime.h>

#define N_SUP 4096
#define N_QRY 8192
#define IN_DIM 784
#define EMB 512
#define NCLS 64
#define M_TOT (N_SUP + N_QRY)
#define NCHUNK 25   // ceil(784/32)
#define XCH 13      // ceil(784/64)

typedef _Float16 f16;
typedef _Float16 f16x8 __attribute__((ext_vector_type(8)));
typedef float f32x4 __attribute__((ext_vector_type(4)));

// async global->LDS, 16B per lane. LDS dest is wave-uniform base + lane*16.
#define GLDS16(gp, lp)                                                        \
    __builtin_amdgcn_global_load_lds(                                         \
        (const __attribute__((address_space(1))) void*)(gp),                  \
        (__attribute__((address_space(3))) void*)(lp), 16, 0, 0)

// counted-vmcnt phase boundary: wait own N-newest-allowed, then block
// barrier, then a full scheduling fence so no LDS read hoists above it.
#define WAITB(N)                                                              \
    asm volatile("s_waitcnt vmcnt(" #N ")" ::: "memory");                     \
    __builtin_amdgcn_s_barrier();                                             \
    __builtin_amdgcn_sched_barrier(0);

// load 8 consecutive fp32 and convert to f16x8
static __device__ __forceinline__ f16x8 cvt8(const float* p) {
    float4 a = *(const float4*)p;
    float4 b = *(const float4*)(p + 4);
    f16x8 v;
    v[0] = (f16)a.x; v[1] = (f16)a.y; v[2] = (f16)a.z; v[3] = (f16)a.w;
    v[4] = (f16)b.x; v[5] = (f16)b.y; v[6] = (f16)b.z; v[7] = (f16)b.w;
    return v;
}

// ---- fused prep: blocks [0,200) = Wb repack, [200,1224) = label argmax ----
__global__ __launch_bounds__(256) void pre_enc(const float* __restrict__ W,
                                               const float* __restrict__ lab,
                                               f16* __restrict__ Wb,
                                               int* __restrict__ lbl) {
    if (blockIdx.x < 200) {
        int g = blockIdx.x * 256 + threadIdx.x;      // 51200 frag-lanes
        if (g >= NCHUNK * 32 * 64) return;
        int chunk = g >> 11;
        int rem = g & 2047;
        int nbg = rem >> 6, lane = rem & 63;
        int n = nbg * 16 + (lane & 15);
        int kbase = chunk * 32 + (lane >> 4) * 8;
        f16x8 v;
#pragma unroll
        for (int j = 0; j < 8; ++j) {
            int k = kbase + j;
            v[j] = (k < IN_DIM) ? (f16)W[(size_t)k * EMB + n] : (f16)0.f;
        }
        *(f16x8*)(Wb + (size_t)g * 8) = v;
    } else {
        const int w = threadIdx.x >> 6, lane = threadIdx.x & 63;
        const int s = (blockIdx.x - 200) * 4 + w;
        float v = lab[(size_t)s * NCLS + lane];
        int c = lane;
#pragma unroll
        for (int off = 1; off < 64; off <<= 1) {
            float v2 = __shfl_xor(v, off);
            int c2 = __shfl_xor(c, off);
            if (v2 > v || (v2 == v && c2 < c)) { v = v2; c = c2; }
        }
        if (lane == 0) lbl[s] = c;
    }
}

// ---- encode: 32 rows x 256 cols per block, grid 768 (3 blocks/CU). ----
__global__ __launch_bounds__(256) void encode(
    const float* __restrict__ sup, const float* __restrict__ qry,
    const f16* __restrict__ Wb, const float* __restrict__ bias,
    f16* __restrict__ E, float* __restrict__ norms)
{
    __shared__ __align__(16) f16 Xs[32][72];
    const int tid = threadIdx.x;
    const int w = tid >> 6, lane = tid & 63;
    const int q = lane >> 4, c16 = lane & 15;
    const int mb = blockIdx.x >> 1;
    const int ch = blockIdx.x & 1;
    const int m0 = mb * 32;
    const int rbase = (w & 1) * 16;
    const int nbg0 = ch * 16 + (w >> 1) * 8;
    const int cbase = nbg0 * 16;

    f32x4 acc[8];
#pragma unroll
    for (int nb = 0; nb < 8; ++nb) acc[nb] = (f32x4){0.f, 0.f, 0.f, 0.f};

    const int sr = tid >> 3;
    const int sq = tid & 7;
    const float* xrow;
    {
        int gr = m0 + sr;
        xrow = (gr < N_SUP) ? sup + (size_t)gr * IN_DIM
                            : qry + (size_t)(gr - N_SUP) * IN_DIM;
    }

    f16x8 xg = cvt8(xrow + sq * 8);

    for (int c = 0; c < XCH; ++c) {
        __syncthreads();
        *(f16x8*)&Xs[sr][sq * 8] = xg;
        __syncthreads();
        if (c + 1 < XCH) {
            int k = (c + 1) * 64 + sq * 8;
            xg = (k + 8 <= IN_DIM) ? cvt8(xrow + k) : (f16x8){0,0,0,0,0,0,0,0};
        }
#pragma unroll
        for (int kc = 0; kc < 2; ++kc) {
            int c32 = c * 2 + kc;
            if (c32 >= NCHUNK) break;
            f16x8 a = *(const f16x8*)&Xs[rbase + c16][kc * 32 + q * 8];
            const f16* wb = Wb + ((size_t)(c32 * 32 + nbg0) * 64 + lane) * 8;
#pragma unroll
            for (int nb = 0; nb < 8; ++nb) {
                f16x8 b = *(const f16x8*)(wb + (size_t)nb * 512);
                acc[nb] = __builtin_amdgcn_mfma_f32_16x16x32_f16(a, b, acc[nb], 0, 0, 0);
            }
        }
    }

    float nrm[4] = {0.f, 0.f, 0.f, 0.f};
#pragma unroll
    for (int nb = 0; nb < 8; ++nb) {
        int col = cbase + nb * 16 + c16;
        float bv = bias[col];
#pragma unroll
        for (int r = 0; r < 4; ++r) {
            int row = m0 + rbase + q * 4 + r;
            float v = acc[nb][r] + bv;
            E[(size_t)row * EMB + col] = (f16)v;
            nrm[r] += v * v;
        }
    }
#pragma unroll
    for (int r = 0; r < 4; ++r) {
        float v = nrm[r];
        v += __shfl_xor(v, 1); v += __shfl_xor(v, 2);
        v += __shfl_xor(v, 4); v += __shfl_xor(v, 8);
        if (c16 == 0) atomicAdd(&norms[m0 + rbase + q * 4 + r], v);
    }
}

// ---- fused post-encode: [0,1024) Sb swizzle, [1024,3072) anchor,
//      [3072,4096) Lcs one-hot transpose ----
__global__ __launch_bounds__(256) void post_enc(
    const f16* __restrict__ E, const float* __restrict__ norms,
    const int* __restrict__ lbl, f16* __restrict__ Sb,
    f16* __restrict__ Lcs, float* __restrict__ manc)
{
    const int b = blockIdx.x;
    if (b < 1024) {
        int g = b * 256 + threadIdx.x;   // 262144 groups of 8 f16
        int s = g >> 6, lg = g & 63;
        f16x8 v = *(const f16x8*)(E + (size_t)s * EMB + lg * 8);
        *(f16x8*)(Sb + (size_t)s * EMB + ((lg ^ (s & 15)) * 8)) = v;
    } else if (b < 3072) {
        const int w = threadIdx.x >> 6, lane = threadIdx.x & 63;
        const int qrow = (b - 1024) * 4 + w;
        f16x8 qv = *(const f16x8*)(E + (size_t)(N_SUP + qrow) * EMB + lane * 8);
        f16x8 sv = *(const f16x8*)(E + lane * 8);
        float dot = 0.f;
#pragma unroll
        for (int j = 0; j < 8; ++j) dot += (float)qv[j] * (float)sv[j];
        dot += __shfl_xor(dot, 1);  dot += __shfl_xor(dot, 2);
        dot += __shfl_xor(dot, 4);  dot += __shfl_xor(dot, 8);
        dot += __shfl_xor(dot, 16); dot += __shfl_xor(dot, 32);
        if (lane == 0) {
            float d2 = fmaxf(norms[N_SUP + qrow] + norms[0] - 2.f * dot, 0.f);
            manc[qrow] = sqrtf(d2);
        }
    } else {
        int idx = (b - 3072) * 256 + threadIdx.x;
        int c = idx >> 12, s = idx & (N_SUP - 1);
        Lcs[idx] = (lbl[s] == c) ? (f16)1.f : (f16)0.f;
    }
}

// ---- attn v8: T3+T4 counted-vmcnt pipeline on the v3 geometry.
// 4-deep LDS ring (4x16KB); each tile issues batch t+3; per-tile boundary is
// s_waitcnt vmcnt(8) (keeps batches t+1,t+2 in flight) + raw s_barrier +
// sched_barrier(0). vmcnt NEVER drains to 0 in the main loop. Rationale:
// v3/v6/v7 all pinned at 86-92us despite different inner loops -> the shared
// 2-phase {stage, compute, drain-barrier} skeleton is the limiter (per-tile
// wall 6.8k cyc vs ~1.7k cyc of pipe work). Safety: batch(t) is >=8 loads
// older than the wait point, so vmcnt(8) guarantees its completion; the
// barrier makes that block-wide. bl prefetch issued BEFORE the batch so the
// compiler's implicit bl-wait at PV keeps the ring full. ----
__global__ __launch_bounds__(256, 2) void attn(
    const f16* __restrict__ E, const float* __restrict__ norms,
    const float* __restrict__ manc, const f16* __restrict__ Lcs,
    const f16* __restrict__ Sb, float* __restrict__ Num)
{
    __shared__ __align__(16) f16 Ss[4][16 * EMB];   // 4 x 16KB ring
    __shared__ __align__(16) f16 Pt[4][16][40];     // per-wave P transpose, 5KB
    __shared__ float Sn[512];                       // support norms slice, 2KB
    const int tid = threadIdx.x;
    const int w = tid >> 6, lane = tid & 63;
    const int q = lane >> 4, c16 = lane & 15;
    const int ss = blockIdx.x & 7;        // XCD %8 residency heuristic
    const int qt = blockIdx.x >> 3;

    // stage this slice's support norms once (published by first WAITB barrier)
    Sn[tid]       = norms[ss * 512 + tid];
    Sn[256 + tid] = norms[ss * 512 + 256 + tid];

    // resident Q fragments (A-layout m=c16): 64 VGPRs
    f16x8 qf[16];
    const f16* qb = E + (size_t)(N_SUP + qt * 64 + w * 16 + c16) * EMB + q * 8;
#pragma unroll
    for (int ks = 0; ks < 16; ++ks) qf[ks] = *(const f16x8*)(qb + ks * 32);
    float q2[4], mrow[4];
#pragma unroll
    for (int r = 0; r < 4; ++r) {
        q2[r]   = norms[N_SUP + qt * 64 + w * 16 + q * 4 + r];
        mrow[r] = manc[qt * 64 + w * 16 + q * 4 + r];
    }

    f32x4 accPL[4];
#pragma unroll
    for (int nb = 0; nb < 4; ++nb) accPL[nb] = (f32x4){0.f, 0.f, 0.f, 0.f};

    const f16* sb_base = Sb + (size_t)(ss * 512) * EMB;
    const int wslot = w * 256;            // wave's 256-slot region (x16B)

    auto ISSUE = [&](int tt) {            // 4 GLDS16 -> Ss[tt&3]
        const f16* gsrc = sb_base + (size_t)tt * 16 * EMB;
#pragma unroll
        for (int i = 0; i < 4; ++i)
            GLDS16(gsrc + (size_t)(wslot + i * 64 + lane) * 8,
                   &Ss[tt & 3][(wslot + i * 64) * 8]);
    };
    auto BL = [&](int p, f16x8* bl) {     // Lcs B-frags for pair p
        const int ps0 = ss * 512 + p * 32;
#pragma unroll
        for (int nbc = 0; nbc < 4; ++nbc)
            bl[nbc] = *(const f16x8*)(Lcs + (size_t)(nbc * 16 + c16) * N_SUP + ps0 + q * 8);
    };
    auto QK = [&](int t) -> f32x4 {       // K=512 x 16 supports from Ss[t&3]
        f32x4 a = (f32x4){0.f, 0.f, 0.f, 0.f};
        const f16* S = &Ss[t & 3][0];
#pragma unroll
        for (int kc = 0; kc < 4; ++kc)
#pragma unroll
            for (int ksl = 0; ksl < 4; ++ksl) {
                const int lg = kc * 16 + ksl * 4 + q;
                f16x8 b = *(const f16x8*)&S[c16 * EMB + ((lg ^ c16) * 8)];
                a = __builtin_amdgcn_mfma_f32_16x16x32_f16(qf[kc * 4 + ksl], b, a, 0, 0, 0);
            }
        return a;
    };
    auto EPI = [&](f32x4 acc, int t) {    // p = exp(m - d) -> Pt half
        const float s2 = Sn[t * 16 + c16];
        const int pcol = (t & 1) * 16 + c16;
#pragma unroll
        for (int r = 0; r < 4; ++r) {
            float d2 = fmaxf(q2[r] + s2 - 2.f * acc[r], 0.f);
            float p = __expf(mrow[r] - __builtin_amdgcn_sqrtf(d2));
            Pt[w][q * 4 + r][pcol] = (f16)fminf(p, 60000.f);
        }
    };
    auto PV = [&](const f16x8* bl) {      // K=32 (two tiles' P) x 4 class-grps
        f16x8 af = *(const f16x8*)&Pt[w][c16][q * 8];
#pragma unroll
        for (int nbc = 0; nbc < 4; ++nbc)
            accPL[nbc] = __builtin_amdgcn_mfma_f32_16x16x32_f16(af, bl[nbc], accPL[nbc], 0, 0, 0);
    };

    // prologue: fill 3 ring slots; Sn must be LDS-visible before barrier 0
    ISSUE(0); ISSUE(1); ISSUE(2);
    asm volatile("s_waitcnt lgkmcnt(0)" ::: "memory");

    f16x8 bl[4];
    for (int tp = 0; tp < 14; ++tp) {
        const int t0 = tp * 2;
        WAITB(8);                          // batch t0 ready (t0+1,t0+2 in flight)
        BL(tp, bl);
        ISSUE(t0 + 3);
        EPI(QK(t0), t0);
        WAITB(8);                          // batch t0+1 ready
        ISSUE(t0 + 4);
        EPI(QK(t0 + 1), t0 + 1);
        PV(bl);
    }
    // peel tiles 28..31 (ring drain: vmcnt 8,8,4,0)
    WAITB(8); BL(14, bl); ISSUE(31); EPI(QK(28), 28);
    WAITB(8); EPI(QK(29), 29); PV(bl);
    WAITB(4); BL(15, bl); EPI(QK(30), 30);
    WAITB(0); EPI(QK(31), 31); PV(bl);

#pragma unroll
    for (int nbc = 0; nbc < 4; ++nbc)
#pragma unroll
        for (int r = 0; r < 4; ++r)
            atomicAdd(&Num[(size_t)(qt * 64 + w * 16 + q * 4 + r) * NCLS + nbc * 16 + c16],
                      accPL[nbc][r]);
}

// ---- finalize: out[q][c] = Num[q][c] / rowsum(Num[q]) ----
__global__ __launch_bounds__(256) void finalize(const float* __restrict__ Num,
                                                float* __restrict__ out) {
    const int tid = threadIdx.x;
    const int w = tid >> 6, lane = tid & 63;
    const int qrow = blockIdx.x * 4 + w;
    float v = Num[(size_t)qrow * NCLS + lane];
    float s = v;
    s += __shfl_xor(s, 1);  s += __shfl_xor(s, 2);  s += __shfl_xor(s, 4);
    s += __shfl_xor(s, 8);  s += __shfl_xor(s, 16); s += __shfl_xor(s, 32);
    out[(size_t)qrow * NCLS + lane] = v / s;
}

extern "C" void kernel_launch(void* const* d_in, const int* in_sizes, int n_in,
                              void* d_out, int out_size, void* d_ws, size_t ws_size,
                              hipStream_t stream) {
    (void)in_sizes; (void)n_in; (void)out_size; (void)ws_size;
    const float* sup  = (const float*)d_in[0];
    const float* qry  = (const float*)d_in[1];
    const float* lab  = (const float*)d_in[2];
    const float* Wenc = (const float*)d_in[3];
    const float* benc = (const float*)d_in[4];
    float* out = (float*)d_out;

    char* ws = (char*)d_ws;
    size_t off = 0;
    f16* Wb = (f16*)(ws + off);        off += (size_t)NCHUNK * 32 * 64 * 8 * 2; // 819200
    f16* E  = (f16*)(ws + off);        off += (size_t)M_TOT * EMB * 2;          // 12582912
    f16* Sb = (f16*)(ws + off);        off += (size_t)N_SUP * EMB * 2;          // 4194304
    int* lbl = (int*)(ws + off);       off += (size_t)N_SUP * 4;                // 16384
    f16* Lcs = (f16*)(ws + off);       off += (size_t)NCLS * N_SUP * 2;         // 524288
    float* manc = (float*)(ws + off);  off += (size_t)N_QRY * 4;                // 32768
    float* norms = (float*)(ws + off); off += (size_t)M_TOT * 4;                // 49152
    float* Num = (float*)(ws + off);   off += (size_t)N_QRY * NCLS * 4;         // 2097152

    // norms and Num adjacent: one memset
    hipMemsetAsync(norms, 0, (size_t)M_TOT * 4 + (size_t)N_QRY * NCLS * 4, stream);

    pre_enc<<<1224, 256, 0, stream>>>(Wenc, lab, Wb, lbl);
    encode<<<M_TOT / 32 * 2, 256, 0, stream>>>(sup, qry, Wb, benc, E, norms);
    post_enc<<<4096, 256, 0, stream>>>(E, norms, lbl, Sb, Lcs, manc);
    attn<<<N_QRY / 64 * 8, 256, 0, stream>>>(E, norms, manc, Lcs, Sb, Num);
    finalize<<<N_QRY / 4, 256, 0, stream>>>(Num, out);
}